// Round 9
// baseline (555.381 us; speedup 1.0000x reference)
//
#include <hip/hip_runtime.h>
#include <hip/hip_bf16.h>

typedef __bf16 bf16;
typedef __bf16 bf16x8 __attribute__((ext_vector_type(8)));
typedef __bf16 bf16x4 __attribute__((ext_vector_type(4)));
typedef __bf16 bf16x2 __attribute__((ext_vector_type(2)));
typedef float f32x4 __attribute__((ext_vector_type(4)));
typedef float f32x16 __attribute__((ext_vector_type(16)));
typedef unsigned int u32x4 __attribute__((ext_vector_type(4)));

#define MFMA_BF16(a, b, c) __builtin_amdgcn_mfma_f32_16x16x32_bf16((a), (b), (c), 0, 0, 0)
#define MFMA32(a, b, c) __builtin_amdgcn_mfma_f32_32x32x16_bf16((a), (b), (c), 0, 0, 0)

#if defined(__has_builtin)
#if __has_builtin(__builtin_amdgcn_exp2f)
#define EXP2F(x) __builtin_amdgcn_exp2f(x)
#endif
#endif
#ifndef EXP2F
#define EXP2F(x) exp2f(x)
#endif

// Problem constants
static constexpr int Bc = 4, Lc = 2048, Dc = 1024, Hc = 16, DKc = 64;
static constexpr int BLc = Bc * Lc;  // 8192
// exp(s/8) == exp2(s * log2(e)/8)
static constexpr float CEXP = 0.18033688011112042f;

__device__ inline unsigned pk2(float a, float b) {
  bf16x2 t;
  t[0] = (bf16)a;
  t[1] = (bf16)b;
  return __builtin_bit_cast(unsigned, t);
}

__device__ __forceinline__ void gload_lds16(const bf16* g, bf16* l) {
  __builtin_amdgcn_global_load_lds(
      (const __attribute__((address_space(1))) void*)g,
      (__attribute__((address_space(3))) void*)l, 16, 0, 0);
}

// ---------------- f32 -> bf16 weight conversion ----------------
__global__ __launch_bounds__(256) void cvt_w(const float* __restrict__ src,
                                             bf16* __restrict__ dst) {
  int i = blockIdx.x * 256 + threadIdx.x;
  float4 f = ((const float4*)src)[i];
  bf16x4 o;
  o[0] = (bf16)f.x; o[1] = (bf16)f.y; o[2] = (bf16)f.z; o[3] = (bf16)f.w;
  *(bf16x4*)(dst + (size_t)i * 4) = o;
}

// ---------------- GEMM: C[M,N] = A[M,K] @ Bw[N,K]^T ----------------
// m97 geometry: 128x128 tile, BK=64, 256 threads / 4 waves (2x2 of 64x64),
// single 32 KB LDS buffer. All bf16 operands staged via global_load_lds
// width=16 (linear LDS dest + inverse-XOR-swizzled per-lane global source);
// f32 A staged via reg-cvt + swizzled ds_write. Read applies the same XOR
// involution: 16B-slot' = slot ^ (row&7).
// OUT_MODE: 0 = bf16 row-major; 1 = f32 + residual; 2 = bf16 transposed into
// vt[b][h][dv][token] with bf16x4 stores along token.
template <int A_F32, int OUT_MODE>
__global__ __launch_bounds__(256) void gemm_gl(const void* __restrict__ Av,
                                               const bf16* __restrict__ Bw,
                                               void* __restrict__ Cv,
                                               const float* __restrict__ resid) {
  __shared__ bf16 As[128 * 64];
  __shared__ bf16 Bs[128 * 64];
  const int t = threadIdx.x;
  const int lane = t & 63, wid = t >> 6;
  const int wr = wid >> 1, wc = wid & 1;
  const int m0 = blockIdx.x * 128, n0 = blockIdx.y * 128;

  f32x4 acc[4][4] = {};

  for (int kt = 0; kt < 1024; kt += 64) {
    // ---- stage B: 4 global_load_lds (16B/lane, linear LDS dest) ----
#pragma unroll
    for (int cgl = 0; cgl < 4; ++cgl) {
      int idx = cgl * 256 + t;  // row = idx>>3, 16B-slot = idx&7
      int row = idx >> 3, slot = idx & 7;
      int scol = (slot ^ (row & 7)) * 8;  // inverse-swizzled source column
      gload_lds16(Bw + (size_t)(n0 + row) * 1024 + kt + scol, Bs + idx * 8);
    }
    // ---- stage A ----
    if (A_F32) {
      const float* A = (const float*)Av;
      const int sub = t & 7, srow0 = t >> 3;
#pragma unroll
      for (int s = 0; s < 4; ++s) {
        int row = srow0 + 32 * s;
        const float4* pa = (const float4*)(A + (size_t)(m0 + row) * 1024 + kt + sub * 8);
        float4 f0 = pa[0], f1 = pa[1];
        bf16x8 o;
        o[0] = (bf16)f0.x; o[1] = (bf16)f0.y; o[2] = (bf16)f0.z; o[3] = (bf16)f0.w;
        o[4] = (bf16)f1.x; o[5] = (bf16)f1.y; o[6] = (bf16)f1.z; o[7] = (bf16)f1.w;
        *(bf16x8*)&As[row * 64 + ((sub ^ (row & 7)) * 8)] = o;
      }
    } else {
      const bf16* A = (const bf16*)Av;
#pragma unroll
      for (int cgl = 0; cgl < 4; ++cgl) {
        int idx = cgl * 256 + t;
        int row = idx >> 3, slot = idx & 7;
        int scol = (slot ^ (row & 7)) * 8;
        gload_lds16(A + (size_t)(m0 + row) * 1024 + kt + scol, As + idx * 8);
      }
    }
    __syncthreads();
    // ---- compute ----
#pragma unroll
    for (int c = 0; c < 2; ++c) {
      const int slot = c * 4 + (lane >> 4);  // desired pre-swizzle 16B slot
      bf16x8 af[4], bfr[4];
#pragma unroll
      for (int m = 0; m < 4; ++m) {
        int row = wr * 64 + m * 16 + (lane & 15);
        af[m] = *(const bf16x8*)&As[row * 64 + ((slot ^ (row & 7)) * 8)];
      }
#pragma unroll
      for (int n = 0; n < 4; ++n) {
        int row = wc * 64 + n * 16 + (lane & 15);
        bfr[n] = *(const bf16x8*)&Bs[row * 64 + ((slot ^ (row & 7)) * 8)];
      }
#pragma unroll
      for (int m = 0; m < 4; ++m)
#pragma unroll
        for (int n = 0; n < 4; ++n)
          acc[m][n] = MFMA_BF16(af[m], bfr[n], acc[m][n]);
    }
    __syncthreads();
  }

  // epilogue: D layout col = lane&15, row = (lane>>4)*4 + r
  const int rbase = m0 + wr * 64 + (lane >> 4) * 4;
  const int cbase = n0 + wc * 64 + (lane & 15);
  if (OUT_MODE == 1) {
    float* C = (float*)Cv;
#pragma unroll
    for (int m = 0; m < 4; ++m)
#pragma unroll
      for (int n = 0; n < 4; ++n)
#pragma unroll
        for (int r = 0; r < 4; ++r) {
          size_t row = (size_t)(rbase + m * 16 + r);
          size_t col = (size_t)(cbase + n * 16);
          C[row * 1024 + col] = acc[m][n][r] + resid[row * 1024 + col];
        }
  } else if (OUT_MODE == 0) {
    bf16* C = (bf16*)Cv;
#pragma unroll
    for (int m = 0; m < 4; ++m)
#pragma unroll
      for (int n = 0; n < 4; ++n)
#pragma unroll
        for (int r = 0; r < 4; ++r) {
          size_t row = (size_t)(rbase + m * 16 + r);
          size_t col = (size_t)(cbase + n * 16);
          C[row * 1024 + col] = (bf16)acc[m][n][r];
        }
  } else {
    // vt[(b*16+h)*64 + dv][token]: r spans 4 consecutive tokens -> bf16x4 store.
    bf16* C = (bf16*)Cv;
#pragma unroll
    for (int m = 0; m < 4; ++m)
#pragma unroll
      for (int n = 0; n < 4; ++n) {
        int row = rbase + m * 16;   // token base (multiple of 4)
        int col = cbase + n * 16;   // h*64 + dv
        bf16x4 o;
#pragma unroll
        for (int r = 0; r < 4; ++r) o[r] = (bf16)acc[m][n][r];
        size_t dst = ((size_t)((row >> 11) << 10) + col) * 2048 + (row & 2047);
        *(bf16x4*)(C + dst) = o;
      }
  }
}

// ---------------- fused attention (byte-identical to R8) ----------------
__global__ __launch_bounds__(256, 3) void attn_kernel(const bf16* __restrict__ qh,
                                                      const bf16* __restrict__ kh,
                                                      const bf16* __restrict__ vt,
                                                      bf16* __restrict__ ctx,
                                                      float* __restrict__ attn_out) {
  __shared__ bf16 Ks[64][72];
  __shared__ bf16 Vs[64][72];  // Vs[dv][token]
  const int t = threadIdx.x, lane = t & 63, w = t >> 6;
  const int hi = lane >> 5, ql = lane & 31;
  const int qt = blockIdx.x, h = blockIdx.y, b = blockIdx.z;
  const size_t rowbase = (size_t)b * 2048;
  const int qrow = qt * 128 + w * 32 + ql;
  const bf16* kbase = kh + rowbase * 1024 + h * 64;
  const bf16* vbase = vt + (size_t)(b * 16 + h) * 64 * 2048;
  const int sub = t & 7, srow = t >> 3;

  bf16x8 qf[4];
  {
    const bf16* qp = qh + (rowbase + qrow) * 1024 + h * 64 + hi * 8;
#pragma unroll
    for (int c = 0; c < 4; ++c) qf[c] = *(const bf16x8*)(qp + c * 16);
  }

  f32x16 cacc[2] = {};
  float zacc = 0.f;

  // ---------- Phase A ----------
  for (int kt = 0; kt < 2048; kt += 64) {
    __syncthreads();
#pragma unroll
    for (int s = 0; s < 2; ++s) {
      int r = srow + 32 * s;
      *(u32x4*)&Ks[r][sub * 8] =
          *(const u32x4*)(kbase + (size_t)(kt + r) * 1024 + sub * 8);
      *(u32x4*)&Vs[r][sub * 8] =
          *(const u32x4*)(vbase + (size_t)r * 2048 + kt + sub * 8);
    }
    __syncthreads();
#pragma unroll
    for (int sb = 0; sb < 2; ++sb) {
      f32x16 s = {};
#pragma unroll
      for (int c = 0; c < 4; ++c) {
        bf16x8 kf = *(const bf16x8*)&Ks[sb * 32 + ql][c * 16 + hi * 8];
        s = MFMA32(kf, qf[c], s);
      }
      float p[16];
#pragma unroll
      for (int j = 0; j < 16; ++j) {
        p[j] = EXP2F(s[j] * CEXP);
        zacc += p[j];
      }
      unsigned pv[4][2];
#pragma unroll
      for (int o = 0; o < 4; ++o)
#pragma unroll
        for (int d = 0; d < 2; ++d) pv[o][d] = pk2(p[o * 4 + 2 * d], p[o * 4 + 2 * d + 1]);
      bf16x8 pa[2];
#pragma unroll
      for (int c = 0; c < 2; ++c) {
        u32x4 pu;
#pragma unroll
        for (int d = 0; d < 2; ++d) {
          unsigned a = pv[2 * c][d], bq = pv[2 * c + 1][d];
          unsigned as = (unsigned)__shfl_xor((int)a, 32);
          unsigned bs = (unsigned)__shfl_xor((int)bq, 32);
          pu[d] = hi ? bs : a;
          pu[2 + d] = hi ? bq : as;
        }
        pa[c] = __builtin_bit_cast(bf16x8, pu);
      }
#pragma unroll
      for (int n = 0; n < 2; ++n)
#pragma unroll
        for (int c = 0; c < 2; ++c) {
          bf16x8 vf = *(const bf16x8*)&Vs[n * 32 + ql][sb * 32 + c * 16 + hi * 8];
          cacc[n] = MFMA32(pa[c], vf, cacc[n]);
        }
    }
  }

  float z = zacc + __shfl_xor(zacc, 32);
  float rz = 1.0f / z;

  // ctx write: cacc[n][g] = ctx[q = crow(g,hi)][dv = n*32 + ql]
  {
    float rzv[16];
#pragma unroll
    for (int g = 0; g < 16; ++g)
      rzv[g] = __shfl(rz, (g & 3) + 8 * (g >> 2) + 4 * hi);
#pragma unroll
    for (int n = 0; n < 2; ++n)
#pragma unroll
      for (int g = 0; g < 16; ++g) {
        int crow = (g & 3) + 8 * (g >> 2) + 4 * hi;
        size_t row = rowbase + (size_t)(qt * 128 + w * 32 + crow);
        ctx[row * 1024 + h * 64 + n * 32 + ql] = (bf16)(cacc[n][g] * rzv[g]);
      }
  }

  // ---------- Phase B: attn = exp(s)/Z, K staged through LDS ----------
  float* abase = attn_out + ((size_t)(b * 16 + h) * 2048 + qrow) * 2048;
  for (int kt = 0; kt < 2048; kt += 64) {
    __syncthreads();  // previous tile fully consumed
#pragma unroll
    for (int s = 0; s < 2; ++s) {
      int r = srow + 32 * s;
      *(u32x4*)&Ks[r][sub * 8] =
          *(const u32x4*)(kbase + (size_t)(kt + r) * 1024 + sub * 8);
    }
    __syncthreads();
#pragma unroll
    for (int sb = 0; sb < 2; ++sb) {
      f32x16 s = {};
#pragma unroll
      for (int c = 0; c < 4; ++c) {
        bf16x8 kf = *(const bf16x8*)&Ks[sb * 32 + ql][c * 16 + hi * 8];
        s = MFMA32(kf, qf[c], s);
      }
#pragma unroll
      for (int o = 0; o < 4; ++o) {
        float4 v4;
        v4.x = EXP2F(s[o * 4 + 0] * CEXP) * rz;
        v4.y = EXP2F(s[o * 4 + 1] * CEXP) * rz;
        v4.z = EXP2F(s[o * 4 + 2] * CEXP) * rz;
        v4.w = EXP2F(s[o * 4 + 3] * CEXP) * rz;
        *(float4*)(abase + kt + sb * 32 + o * 8 + hi * 4) = v4;
      }
    }
  }
}

// ---------------- LayerNorm (in-place on d_out rows) ----------------
__global__ __launch_bounds__(256) void ln_kernel(float* __restrict__ io,
                                                 const float* __restrict__ g,
                                                 const float* __restrict__ bta) {
  const int row = blockIdx.x, t = threadIdx.x;
  float4* rp = (float4*)(io + (size_t)row * 1024);
  float4 v = rp[t];
  float s = v.x + v.y + v.z + v.w;
  float s2 = v.x * v.x + v.y * v.y + v.z * v.z + v.w * v.w;
#pragma unroll
  for (int off = 32; off >= 1; off >>= 1) {
    s += __shfl_xor(s, off);
    s2 += __shfl_xor(s2, off);
  }
  __shared__ float ls[4], ls2[4];
  const int w = t >> 6;
  if ((t & 63) == 0) { ls[w] = s; ls2[w] = s2; }
  __syncthreads();
  s = ls[0] + ls[1] + ls[2] + ls[3];
  s2 = ls2[0] + ls2[1] + ls2[2] + ls2[3];
  float mu = s * (1.f / 1024.f);
  float var = s2 * (1.f / 1024.f) - mu * mu;
  float rs = rsqrtf(var + 1e-6f);
  float4 gv = ((const float4*)g)[t];
  float4 bv = ((const float4*)bta)[t];
  v.x = (v.x - mu) * rs * gv.x + bv.x;
  v.y = (v.y - mu) * rs * gv.y + bv.y;
  v.z = (v.z - mu) * rs * gv.z + bv.z;
  v.w = (v.w - mu) * rs * gv.w + bv.w;
  rp[t] = v;
}

extern "C" void kernel_launch(void* const* d_in, const int* in_sizes, int n_in,
                              void* d_out, int out_size, void* d_ws, size_t ws_size,
                              hipStream_t stream) {
  (void)in_sizes; (void)n_in; (void)out_size; (void)ws_size;
  const float* q    = (const float*)d_in[0];
  const float* k    = (const float*)d_in[1];
  const float* v    = (const float*)d_in[2];
  const float* Wq   = (const float*)d_in[3];
  const float* Wk   = (const float*)d_in[4];
  const float* Wv   = (const float*)d_in[5];
  const float* Wfc  = (const float*)d_in[6];
  const float* ln_g = (const float*)d_in[7];
  const float* ln_b = (const float*)d_in[8];

  char* ws = (char*)d_ws;
  const size_t MB = 1024ull * 1024ull;
  bf16* wqb  = (bf16*)(ws + 0 * MB);
  bf16* wkb  = (bf16*)(ws + 2 * MB);
  bf16* wvb  = (bf16*)(ws + 4 * MB);
  bf16* wfcb = (bf16*)(ws + 6 * MB);
  bf16* qh   = (bf16*)(ws + 8 * MB);   // [8192][1024] bf16
  bf16* kh   = (bf16*)(ws + 24 * MB);
  bf16* vt   = (bf16*)(ws + 40 * MB);  // [4096][2048] transposed V
  bf16* ctx  = (bf16*)(ws + 56 * MB);  // ends at 72 MB

  float* outp  = (float*)d_out;
  float* attnp = outp + (size_t)BLc * Dc;

  cvt_w<<<1024, 256, 0, stream>>>(Wq, wqb);
  cvt_w<<<1024, 256, 0, stream>>>(Wk, wkb);
  cvt_w<<<1024, 256, 0, stream>>>(Wv, wvb);
  cvt_w<<<1024, 256, 0, stream>>>(Wfc, wfcb);

  dim3 gg(64, 8);
  gemm_gl<1, 0><<<gg, 256, 0, stream>>>(q, wqb, qh, nullptr);
  gemm_gl<1, 0><<<gg, 256, 0, stream>>>(k, wkb, kh, nullptr);
  gemm_gl<1, 2><<<gg, 256, 0, stream>>>(v, wvb, vt, nullptr);

  attn_kernel<<<dim3(16, 16, 4), 256, 0, stream>>>(qh, kh, vt, ctx, attnp);

  gemm_gl<0, 1><<<gg, 256, 0, stream>>>(ctx, wfcb, outp, q);
  ln_kernel<<<8192, 256, 0, stream>>>(outp, ln_g, ln_b);
}

// Round 10
// 480.453 us; speedup vs baseline: 1.1560x; 1.1560x over previous
//
#include <hip/hip_runtime.h>
#include <hip/hip_bf16.h>

typedef __bf16 bf16;
typedef __bf16 bf16x8 __attribute__((ext_vector_type(8)));
typedef __bf16 bf16x4 __attribute__((ext_vector_type(4)));
typedef __bf16 bf16x2 __attribute__((ext_vector_type(2)));
typedef float f32x4 __attribute__((ext_vector_type(4)));
typedef float f32x16 __attribute__((ext_vector_type(16)));
typedef unsigned int u32x4 __attribute__((ext_vector_type(4)));

#define MFMA_BF16(a, b, c) __builtin_amdgcn_mfma_f32_16x16x32_bf16((a), (b), (c), 0, 0, 0)
#define MFMA32(a, b, c) __builtin_amdgcn_mfma_f32_32x32x16_bf16((a), (b), (c), 0, 0, 0)

#if defined(__has_builtin)
#if __has_builtin(__builtin_amdgcn_exp2f)
#define EXP2F(x) __builtin_amdgcn_exp2f(x)
#endif
#endif
#ifndef EXP2F
#define EXP2F(x) exp2f(x)
#endif

// Problem constants
static constexpr int Bc = 4, Lc = 2048, Dc = 1024, Hc = 16, DKc = 64;
static constexpr int BLc = Bc * Lc;  // 8192
// exp(s/8) == exp2(s * log2(e)/8)
static constexpr float CEXP = 0.18033688011112042f;

__device__ inline unsigned pk2(float a, float b) {
  bf16x2 t;
  t[0] = (bf16)a;
  t[1] = (bf16)b;
  return __builtin_bit_cast(unsigned, t);
}

// ---------------- all four weight matrices f32 -> bf16, one launch ----------
// Each weight is exactly 1M elements; dst regions contiguous (2 MB apart).
__global__ __launch_bounds__(256) void cvt_all(const float* __restrict__ s0,
                                               const float* __restrict__ s1,
                                               const float* __restrict__ s2,
                                               const float* __restrict__ s3,
                                               bf16* __restrict__ dst) {
  size_t i = ((size_t)blockIdx.x * 256 + threadIdx.x) * 8;
  const float* srcs[4] = {s0, s1, s2, s3};
  const float* sp = srcs[i >> 20] + (i & 1048575);
  float4 f0 = ((const float4*)sp)[0];
  float4 f1 = ((const float4*)sp)[1];
  bf16x8 o;
  o[0] = (bf16)f0.x; o[1] = (bf16)f0.y; o[2] = (bf16)f0.z; o[3] = (bf16)f0.w;
  o[4] = (bf16)f1.x; o[5] = (bf16)f1.y; o[6] = (bf16)f1.z; o[7] = (bf16)f1.w;
  *(bf16x8*)(dst + i) = o;
}

// ---------------- merged QKV projection (R8 gemm body, 1 launch) -------------
// grid (64, 24): y>>3 selects {q,k,v}; n0 = (y&7)*128. v-output goes to
// vt[b][h][dv][token] (bf16x4 along token); q/k row-major.
__global__ __launch_bounds__(256) void qkv_gemm(const float* __restrict__ qin,
                                                const float* __restrict__ kin,
                                                const float* __restrict__ vin,
                                                const bf16* __restrict__ Wb,
                                                bf16* __restrict__ qh,
                                                bf16* __restrict__ kh,
                                                bf16* __restrict__ vt) {
  __shared__ bf16 As[128][72];
  __shared__ bf16 Bs[128][72];
  const int t = threadIdx.x;
  const int lane = t & 63, wid = t >> 6;
  const int wr = wid >> 1, wc = wid & 1;
  const int which = blockIdx.y >> 3;
  const int m0 = blockIdx.x * 128, n0 = (blockIdx.y & 7) * 128;
  const float* A = which == 0 ? qin : which == 1 ? kin : vin;
  const bf16* Bw = Wb + ((size_t)which << 20);
  const int sub = t & 7, srow = t >> 3;

  f32x4 acc[4][4] = {};

  for (int kt = 0; kt < 1024; kt += 64) {
#pragma unroll
    for (int s = 0; s < 4; ++s) {
      int r = srow + 32 * s;
      const float4* pa = (const float4*)(A + (size_t)(m0 + r) * 1024 + kt + sub * 8);
      float4 f0 = pa[0], f1 = pa[1];
      bf16x8 o;
      o[0] = (bf16)f0.x; o[1] = (bf16)f0.y; o[2] = (bf16)f0.z; o[3] = (bf16)f0.w;
      o[4] = (bf16)f1.x; o[5] = (bf16)f1.y; o[6] = (bf16)f1.z; o[7] = (bf16)f1.w;
      *(bf16x8*)&As[r][sub * 8] = o;
    }
#pragma unroll
    for (int s = 0; s < 4; ++s) {
      int r = srow + 32 * s;
      u32x4 u = *(const u32x4*)(Bw + (size_t)(n0 + r) * 1024 + kt + sub * 8);
      *(u32x4*)&Bs[r][sub * 8] = u;
    }
    __syncthreads();
#pragma unroll
    for (int c = 0; c < 2; ++c) {
      const int ko = c * 32 + (lane >> 4) * 8;
      bf16x8 af[4], bfr[4];
#pragma unroll
      for (int m = 0; m < 4; ++m)
        af[m] = *(const bf16x8*)&As[wr * 64 + m * 16 + (lane & 15)][ko];
#pragma unroll
      for (int n = 0; n < 4; ++n)
        bfr[n] = *(const bf16x8*)&Bs[wc * 64 + n * 16 + (lane & 15)][ko];
#pragma unroll
      for (int m = 0; m < 4; ++m)
#pragma unroll
        for (int n = 0; n < 4; ++n)
          acc[m][n] = MFMA_BF16(af[m], bfr[n], acc[m][n]);
    }
    __syncthreads();
  }

  const int rbase = m0 + wr * 64 + (lane >> 4) * 4;
  const int cbase = n0 + wc * 64 + (lane & 15);
  if (which < 2) {
    bf16* C = which == 0 ? qh : kh;
#pragma unroll
    for (int m = 0; m < 4; ++m)
#pragma unroll
      for (int n = 0; n < 4; ++n)
#pragma unroll
        for (int r = 0; r < 4; ++r) {
          size_t row = (size_t)(rbase + m * 16 + r);
          size_t col = (size_t)(cbase + n * 16);
          C[row * 1024 + col] = (bf16)acc[m][n][r];
        }
  } else {
    // vt[(b*16+h)*64 + dv][token]: r spans 4 consecutive tokens -> bf16x4 store.
#pragma unroll
    for (int m = 0; m < 4; ++m)
#pragma unroll
      for (int n = 0; n < 4; ++n) {
        int row = rbase + m * 16;   // token base (multiple of 4)
        int col = cbase + n * 16;   // h*64 + dv
        bf16x4 o;
#pragma unroll
        for (int r = 0; r < 4; ++r) o[r] = (bf16)acc[m][n][r];
        size_t dst = ((size_t)((row >> 11) << 10) + col) * 2048 + (row & 2047);
        *(bf16x4*)(vt + dst) = o;
      }
  }
}

// ---------------- fc GEMM (R8's reg-staged gemm128, f32+residual out) --------
__global__ __launch_bounds__(256) void fc_gemm(const bf16* __restrict__ A,
                                               const bf16* __restrict__ Bw,
                                               float* __restrict__ C,
                                               const float* __restrict__ resid) {
  __shared__ bf16 As[128][72];
  __shared__ bf16 Bs[128][72];
  const int t = threadIdx.x;
  const int lane = t & 63, wid = t >> 6;
  const int wr = wid >> 1, wc = wid & 1;
  const int m0 = blockIdx.x * 128, n0 = blockIdx.y * 128;
  const int sub = t & 7, srow = t >> 3;

  f32x4 acc[4][4] = {};

  for (int kt = 0; kt < 1024; kt += 64) {
#pragma unroll
    for (int s = 0; s < 4; ++s) {
      int r = srow + 32 * s;
      u32x4 u = *(const u32x4*)(A + (size_t)(m0 + r) * 1024 + kt + sub * 8);
      *(u32x4*)&As[r][sub * 8] = u;
    }
#pragma unroll
    for (int s = 0; s < 4; ++s) {
      int r = srow + 32 * s;
      u32x4 u = *(const u32x4*)(Bw + (size_t)(n0 + r) * 1024 + kt + sub * 8);
      *(u32x4*)&Bs[r][sub * 8] = u;
    }
    __syncthreads();
#pragma unroll
    for (int c = 0; c < 2; ++c) {
      const int ko = c * 32 + (lane >> 4) * 8;
      bf16x8 af[4], bfr[4];
#pragma unroll
      for (int m = 0; m < 4; ++m)
        af[m] = *(const bf16x8*)&As[wr * 64 + m * 16 + (lane & 15)][ko];
#pragma unroll
      for (int n = 0; n < 4; ++n)
        bfr[n] = *(const bf16x8*)&Bs[wc * 64 + n * 16 + (lane & 15)][ko];
#pragma unroll
      for (int m = 0; m < 4; ++m)
#pragma unroll
        for (int n = 0; n < 4; ++n)
          acc[m][n] = MFMA_BF16(af[m], bfr[n], acc[m][n]);
    }
    __syncthreads();
  }

  const int rbase = m0 + wr * 64 + (lane >> 4) * 4;
  const int cbase = n0 + wc * 64 + (lane & 15);
#pragma unroll
  for (int m = 0; m < 4; ++m)
#pragma unroll
    for (int n = 0; n < 4; ++n)
#pragma unroll
      for (int r = 0; r < 4; ++r) {
        size_t row = (size_t)(rbase + m * 16 + r);
        size_t col = (size_t)(cbase + n * 16);
        C[row * 1024 + col] = acc[m][n][r] + resid[row * 1024 + col];
      }
}

// ---------------- fused attention (phase A identical to R8) ----------------
// Phase B: stage 128 K-rows per barrier pair (Vs reused as K rows 64-127),
// halving phase-B barrier count 32 -> 16.
__global__ __launch_bounds__(256, 3) void attn_kernel(const bf16* __restrict__ qh,
                                                      const bf16* __restrict__ kh,
                                                      const bf16* __restrict__ vt,
                                                      bf16* __restrict__ ctx,
                                                      float* __restrict__ attn_out) {
  __shared__ bf16 Ks[64][72];
  __shared__ bf16 Vs[64][72];  // phase A: Vs[dv][token]; phase B: K rows 64-127
  const int t = threadIdx.x, lane = t & 63, w = t >> 6;
  const int hi = lane >> 5, ql = lane & 31;
  const int qt = blockIdx.x, h = blockIdx.y, b = blockIdx.z;
  const size_t rowbase = (size_t)b * 2048;
  const int qrow = qt * 128 + w * 32 + ql;
  const bf16* kbase = kh + rowbase * 1024 + h * 64;
  const bf16* vbase = vt + (size_t)(b * 16 + h) * 64 * 2048;
  const int sub = t & 7, srow = t >> 3;

  bf16x8 qf[4];
  {
    const bf16* qp = qh + (rowbase + qrow) * 1024 + h * 64 + hi * 8;
#pragma unroll
    for (int c = 0; c < 4; ++c) qf[c] = *(const bf16x8*)(qp + c * 16);
  }

  f32x16 cacc[2] = {};
  float zacc = 0.f;

  // ---------- Phase A ----------
  for (int kt = 0; kt < 2048; kt += 64) {
    __syncthreads();
#pragma unroll
    for (int s = 0; s < 2; ++s) {
      int r = srow + 32 * s;
      *(u32x4*)&Ks[r][sub * 8] =
          *(const u32x4*)(kbase + (size_t)(kt + r) * 1024 + sub * 8);
      *(u32x4*)&Vs[r][sub * 8] =
          *(const u32x4*)(vbase + (size_t)r * 2048 + kt + sub * 8);
    }
    __syncthreads();
#pragma unroll
    for (int sb = 0; sb < 2; ++sb) {
      f32x16 s = {};
#pragma unroll
      for (int c = 0; c < 4; ++c) {
        bf16x8 kf = *(const bf16x8*)&Ks[sb * 32 + ql][c * 16 + hi * 8];
        s = MFMA32(kf, qf[c], s);
      }
      float p[16];
#pragma unroll
      for (int j = 0; j < 16; ++j) {
        p[j] = EXP2F(s[j] * CEXP);
        zacc += p[j];
      }
      unsigned pv[4][2];
#pragma unroll
      for (int o = 0; o < 4; ++o)
#pragma unroll
        for (int d = 0; d < 2; ++d) pv[o][d] = pk2(p[o * 4 + 2 * d], p[o * 4 + 2 * d + 1]);
      bf16x8 pa[2];
#pragma unroll
      for (int c = 0; c < 2; ++c) {
        u32x4 pu;
#pragma unroll
        for (int d = 0; d < 2; ++d) {
          unsigned a = pv[2 * c][d], bq = pv[2 * c + 1][d];
          unsigned as = (unsigned)__shfl_xor((int)a, 32);
          unsigned bs = (unsigned)__shfl_xor((int)bq, 32);
          pu[d] = hi ? bs : a;
          pu[2 + d] = hi ? bq : as;
        }
        pa[c] = __builtin_bit_cast(bf16x8, pu);
      }
#pragma unroll
      for (int n = 0; n < 2; ++n)
#pragma unroll
        for (int c = 0; c < 2; ++c) {
          bf16x8 vf = *(const bf16x8*)&Vs[n * 32 + ql][sb * 32 + c * 16 + hi * 8];
          cacc[n] = MFMA32(pa[c], vf, cacc[n]);
        }
    }
  }

  float z = zacc + __shfl_xor(zacc, 32);
  float rz = 1.0f / z;

  // ctx write: cacc[n][g] = ctx[q = crow(g,hi)][dv = n*32 + ql]
  {
    float rzv[16];
#pragma unroll
    for (int g = 0; g < 16; ++g)
      rzv[g] = __shfl(rz, (g & 3) + 8 * (g >> 2) + 4 * hi);
#pragma unroll
    for (int n = 0; n < 2; ++n)
#pragma unroll
      for (int g = 0; g < 16; ++g) {
        int crow = (g & 3) + 8 * (g >> 2) + 4 * hi;
        size_t row = rowbase + (size_t)(qt * 128 + w * 32 + crow);
        ctx[row * 1024 + h * 64 + n * 32 + ql] = (bf16)(cacc[n][g] * rzv[g]);
      }
  }

  // ---------- Phase B: attn = exp(s)/Z, 128 K-rows per barrier pair ----------
  float* abase = attn_out + ((size_t)(b * 16 + h) * 2048 + qrow) * 2048;
  for (int kt = 0; kt < 2048; kt += 128) {
    __syncthreads();  // previous 128-row chunk fully consumed
#pragma unroll
    for (int s = 0; s < 2; ++s) {
      int r = srow + 32 * s;
      *(u32x4*)&Ks[r][sub * 8] =
          *(const u32x4*)(kbase + (size_t)(kt + r) * 1024 + sub * 8);
      *(u32x4*)&Vs[r][sub * 8] =
          *(const u32x4*)(kbase + (size_t)(kt + 64 + r) * 1024 + sub * 8);
    }
    __syncthreads();
#pragma unroll
    for (int half = 0; half < 2; ++half) {
      const bf16(*Kb)[72] = half ? Vs : Ks;
      const int kbase_off = kt + half * 64;
#pragma unroll
      for (int sb = 0; sb < 2; ++sb) {
        f32x16 s = {};
#pragma unroll
        for (int c = 0; c < 4; ++c) {
          bf16x8 kf = *(const bf16x8*)&Kb[sb * 32 + ql][c * 16 + hi * 8];
          s = MFMA32(kf, qf[c], s);
        }
#pragma unroll
        for (int o = 0; o < 4; ++o) {
          float4 v4;
          v4.x = EXP2F(s[o * 4 + 0] * CEXP) * rz;
          v4.y = EXP2F(s[o * 4 + 1] * CEXP) * rz;
          v4.z = EXP2F(s[o * 4 + 2] * CEXP) * rz;
          v4.w = EXP2F(s[o * 4 + 3] * CEXP) * rz;
          *(float4*)(abase + kbase_off + sb * 32 + o * 8 + hi * 4) = v4;
        }
      }
    }
  }
}

// ---------------- LayerNorm (in-place on d_out rows) ----------------
__global__ __launch_bounds__(256) void ln_kernel(float* __restrict__ io,
                                                 const float* __restrict__ g,
                                                 const float* __restrict__ bta) {
  const int row = blockIdx.x, t = threadIdx.x;
  float4* rp = (float4*)(io + (size_t)row * 1024);
  float4 v = rp[t];
  float s = v.x + v.y + v.z + v.w;
  float s2 = v.x * v.x + v.y * v.y + v.z * v.z + v.w * v.w;
#pragma unroll
  for (int off = 32; off >= 1; off >>= 1) {
    s += __shfl_xor(s, off);
    s2 += __shfl_xor(s2, off);
  }
  __shared__ float ls[4], ls2[4];
  const int w = t >> 6;
  if ((t & 63) == 0) { ls[w] = s; ls2[w] = s2; }
  __syncthreads();
  s = ls[0] + ls[1] + ls[2] + ls[3];
  s2 = ls2[0] + ls2[1] + ls2[2] + ls2[3];
  float mu = s * (1.f / 1024.f);
  float var = s2 * (1.f / 1024.f) - mu * mu;
  float rs = rsqrtf(var + 1e-6f);
  float4 gv = ((const float4*)g)[t];
  float4 bv = ((const float4*)bta)[t];
  v.x = (v.x - mu) * rs * gv.x + bv.x;
  v.y = (v.y - mu) * rs * gv.y + bv.y;
  v.z = (v.z - mu) * rs * gv.z + bv.z;
  v.w = (v.w - mu) * rs * gv.w + bv.w;
  rp[t] = v;
}

extern "C" void kernel_launch(void* const* d_in, const int* in_sizes, int n_in,
                              void* d_out, int out_size, void* d_ws, size_t ws_size,
                              hipStream_t stream) {
  (void)in_sizes; (void)n_in; (void)out_size; (void)ws_size;
  const float* q    = (const float*)d_in[0];
  const float* k    = (const float*)d_in[1];
  const float* v    = (const float*)d_in[2];
  const float* Wq   = (const float*)d_in[3];
  const float* Wk   = (const float*)d_in[4];
  const float* Wv   = (const float*)d_in[5];
  const float* Wfc  = (const float*)d_in[6];
  const float* ln_g = (const float*)d_in[7];
  const float* ln_b = (const float*)d_in[8];

  char* ws = (char*)d_ws;
  const size_t MB = 1024ull * 1024ull;
  bf16* wall = (bf16*)(ws + 0 * MB);   // wq|wk|wv|wfc contiguous, 2 MB each
  bf16* wfcb = (bf16*)(ws + 6 * MB);
  bf16* qh   = (bf16*)(ws + 8 * MB);   // [8192][1024] bf16
  bf16* kh   = (bf16*)(ws + 24 * MB);
  bf16* vt   = (bf16*)(ws + 40 * MB);  // [4096][2048] transposed V
  bf16* ctx  = (bf16*)(ws + 56 * MB);  // ends at 72 MB

  float* outp  = (float*)d_out;
  float* attnp = outp + (size_t)BLc * Dc;

  cvt_all<<<2048, 256, 0, stream>>>(Wq, Wk, Wv, Wfc, wall);

  qkv_gemm<<<dim3(64, 24), 256, 0, stream>>>(q, k, v, wall, qh, kh, vt);

  attn_kernel<<<dim3(16, 16, 4), 256, 0, stream>>>(qh, kh, vt, ctx, attnp);

  fc_gemm<<<dim3(64, 8), 256, 0, stream>>>(ctx, wfcb, outp, q);
  ln_kernel<<<8192, 256, 0, stream>>>(outp, ln_g, ln_b);
}